// Round 2
// baseline (6492.838 us; speedup 1.0000x reference)
//
#include <hip/hip_runtime.h>

#define N_NODES 32768
#define M_EDGES 8192
#define IN_DIM  256
#define OUT_F   64

#define NBLK   (N_NODES / 64)   // 512 row-stripe blocks (64 rows each)
#define NSTR   (M_EDGES / 32)   // 256 column stripes (32 cols each)
#define ROWCAP 6144             // per-row-block nz capacity (mean 5243, +12.5 sigma)
#define COLCAP 12288            // per-col-stripe nz capacity (mean 10486, +17.6 sigma)

// ---------------------------------------------------------------------------
// Pass 1: single BW-bound scan of H (the ONLY full read of the 1 GiB matrix).
// Block = 64 rows x all 8192 cols, 512 threads (8 waves), float4 loads.
// Produces: Dv_raw[n] (wave row-reduce, no atomics), row-grouped nz list
// (per-block bucket via LDS counter), column-stripe-bucketed nz list
// (global atomic bump over 256 stripe counters).
// ---------------------------------------------------------------------------
__device__ __forceinline__ void push_nz(int rr, int n, int m,
                                        unsigned* rl, unsigned* qc_p,
                                        unsigned* __restrict__ collist,
                                        unsigned* __restrict__ scnt) {
    unsigned p = atomicAdd(qc_p, 1u);                       // LDS counter
    if (p < ROWCAP) rl[p] = ((unsigned)rr << 13) | (unsigned)m;
    int s = m >> 5;
    unsigned p2 = atomicAdd(&scnt[s], 1u);                  // global counter
    if (p2 < COLCAP)
        collist[(size_t)s * COLCAP + p2] = ((unsigned)n << 5) | (unsigned)(m & 31);
}

__global__ __launch_bounds__(512) void k_scan(const float* __restrict__ H,
                                              const float* __restrict__ w,
                                              float* __restrict__ Dv_raw,
                                              unsigned* __restrict__ rowlist,
                                              unsigned* __restrict__ rowcnt,
                                              unsigned* __restrict__ collist,
                                              unsigned* __restrict__ scnt) {
    __shared__ unsigned qc;
    int tid  = threadIdx.x;
    int lane = tid & 63;
    int wid  = tid >> 6;
    if (tid == 0) qc = 0;
    __syncthreads();
    int row0 = blockIdx.x * 64;
    unsigned* rl = rowlist + (size_t)blockIdx.x * ROWCAP;

    for (int rr = wid; rr < 64; rr += 8) {                  // wave owns rows rr ≡ wid (mod 8)
        int n = row0 + rr;
        const float4* Hrow = (const float4*)(H + (size_t)n * M_EDGES);
        float dv = 0.f;
        for (int jb = 0; jb < M_EDGES / 4; jb += 256) {     // 8 groups of 4 float4 loads
            float4 h0 = Hrow[jb + lane];
            float4 h1 = Hrow[jb + 64 + lane];
            float4 h2 = Hrow[jb + 128 + lane];
            float4 h3 = Hrow[jb + 192 + lane];
            #define PROC(hv, j4)                                               \
            if (hv.x != 0.f || hv.y != 0.f || hv.z != 0.f || hv.w != 0.f) {    \
                int mb = (j4) * 4;                                             \
                if (hv.x != 0.f) { dv += w[mb];     push_nz(rr, n, mb,     rl, &qc, collist, scnt); } \
                if (hv.y != 0.f) { dv += w[mb + 1]; push_nz(rr, n, mb + 1, rl, &qc, collist, scnt); } \
                if (hv.z != 0.f) { dv += w[mb + 2]; push_nz(rr, n, mb + 2, rl, &qc, collist, scnt); } \
                if (hv.w != 0.f) { dv += w[mb + 3]; push_nz(rr, n, mb + 3, rl, &qc, collist, scnt); } \
            }
            PROC(h0, jb + lane)
            PROC(h1, jb + 64 + lane)
            PROC(h2, jb + 128 + lane)
            PROC(h3, jb + 192 + lane)
            #undef PROC
        }
        for (int off = 32; off; off >>= 1) dv += __shfl_down(dv, off, 64);
        if (lane == 0) Dv_raw[n] = dv;
    }
    __syncthreads();
    if (tid == 0) rowcnt[blockIdx.x] = (qc < (unsigned)ROWCAP) ? qc : (unsigned)ROWCAP;
}

// ---------------------------------------------------------------------------
// Pass 2: z[n,k] = rsqrt(max(Dv[n],1e-6)) * (x[n,:] @ W[:,k] + b[k])
// ---------------------------------------------------------------------------
__global__ __launch_bounds__(256) void k_lin(const float* __restrict__ x,
                                             const float* __restrict__ Wl,
                                             const float* __restrict__ b,
                                             const float* __restrict__ Dv_raw,
                                             float* __restrict__ z) {
    __shared__ float x_s[4 * IN_DIM];
    int tid = threadIdx.x;
    int n0 = blockIdx.x * 4;
    for (int i = 0; i < 4; ++i)
        x_s[i * IN_DIM + tid] = x[(size_t)(n0 + i) * IN_DIM + tid];
    __syncthreads();
    int r = tid >> 6;
    int k = tid & 63;
    float acc = b[k];
    const float* xr = x_s + r * IN_DIM;
    #pragma unroll 8
    for (int i = 0; i < IN_DIM; ++i)
        acc = fmaf(xr[i], Wl[i * OUT_F + k], acc);
    float dvis = rsqrtf(fmaxf(Dv_raw[n0 + r], 1e-6f));
    z[(size_t)(n0 + r) * OUT_F + k] = dvis * acc;
}

// ---------------------------------------------------------------------------
// Pass 3: t[m,:] = sum_n H[n,m] * z[n,:] from the column-stripe buckets.
// Also counts De[m]. Block = (stripe, chunk-of-entries). LDS t-tile, merged
// into global t with atomics (t was memset to 0).
// ---------------------------------------------------------------------------
__global__ __launch_bounds__(512) void k_edge_sp(const unsigned* __restrict__ collist,
                                                 const unsigned* __restrict__ scnt,
                                                 const float* __restrict__ z,
                                                 float* __restrict__ t,
                                                 unsigned* __restrict__ De_cnt) {
    __shared__ float t_s[32 * OUT_F];    // 8 KB
    __shared__ unsigned de_s[32];
    int tid  = threadIdx.x;
    int lane = tid & 63;
    int wid  = tid >> 6;
    int s = blockIdx.x;
    unsigned cnt = scnt[s]; if (cnt > COLCAP) cnt = COLCAP;
    unsigned nch = gridDim.y;
    unsigned per = (cnt + nch - 1) / nch;
    unsigned begin = blockIdx.y * per;
    unsigned end = begin + per; if (end > cnt) end = cnt;
    if (begin > cnt) begin = cnt;

    for (int i = tid; i < 32 * OUT_F; i += 512) t_s[i] = 0.f;
    if (tid < 32) de_s[tid] = 0;
    __syncthreads();

    const unsigned* cl = collist + (size_t)s * COLCAP;
    for (unsigned base = begin + (unsigned)wid * 64u; base < end; base += 8u * 64u) {
        unsigned rem = end - base; if (rem > 64u) rem = 64u;
        unsigned e = (lane < (int)rem) ? cl[base + lane] : 0u;   // coalesced batch
        for (unsigned j = 0; j < rem; ++j) {
            unsigned ej = (unsigned)__shfl((int)e, (int)j, 64);
            int n = (int)(ej >> 5);
            int c = (int)(ej & 31u);
            float v = z[(size_t)n * OUT_F + lane];
            atomicAdd(&t_s[c * OUT_F + lane], v);                // 2 lanes/bank: free
            if (lane == 0) atomicAdd(&de_s[c], 1u);
        }
    }
    __syncthreads();
    for (int i = tid; i < 32 * OUT_F; i += 512)
        atomicAdd(&t[(size_t)s * (32 * OUT_F) + i], t_s[i]);
    if (tid < 32 && de_s[tid]) atomicAdd(&De_cnt[s * 32 + tid], de_s[tid]);
}

// ---------------------------------------------------------------------------
// Pass 4: out[n,:] = dvis[n] * sum_m H[n,m] * (w[m]/De[m]) * t[m,:]
// from the row-grouped buckets (1:1 with scan blocks). No global atomics.
// ---------------------------------------------------------------------------
__global__ __launch_bounds__(512) void k_node_sp(const unsigned* __restrict__ rowlist,
                                                 const unsigned* __restrict__ rowcnt,
                                                 const float* __restrict__ t,
                                                 const float* __restrict__ w,
                                                 const unsigned* __restrict__ De_cnt,
                                                 const float* __restrict__ Dv_raw,
                                                 float* __restrict__ out) {
    __shared__ float o_s[64 * OUT_F];    // 16 KB
    int tid  = threadIdx.x;
    int lane = tid & 63;
    int wid  = tid >> 6;
    int b = blockIdx.x;
    unsigned cnt = rowcnt[b];
    for (int i = tid; i < 64 * OUT_F; i += 512) o_s[i] = 0.f;
    __syncthreads();

    const unsigned* rl = rowlist + (size_t)b * ROWCAP;
    for (unsigned base = (unsigned)wid * 64u; base < cnt; base += 512u) {
        unsigned rem = cnt - base; if (rem > 64u) rem = 64u;
        unsigned e = (lane < (int)rem) ? rl[base + lane] : 0u;
        for (unsigned j = 0; j < rem; ++j) {
            unsigned ej = (unsigned)__shfl((int)e, (int)j, 64);
            int r = (int)(ej >> 13);
            int m = (int)(ej & (M_EDGES - 1u));
            float sc = w[m] / fmaxf((float)De_cnt[m], 1.f);      // wave-uniform
            float v = t[(size_t)m * OUT_F + lane] * sc;
            atomicAdd(&o_s[r * OUT_F + lane], v);                // 2 lanes/bank: free
        }
    }
    __syncthreads();
    int n0 = b * 64;
    for (int i = tid; i < 64 * OUT_F; i += 512) {
        int r = i >> 6;
        float dvis = rsqrtf(fmaxf(Dv_raw[n0 + r], 1e-6f));
        out[(size_t)n0 * OUT_F + i] = dvis * o_s[i];
    }
}

// ---------------------------------------------------------------------------
extern "C" void kernel_launch(void* const* d_in, const int* in_sizes, int n_in,
                              void* d_out, int out_size, void* d_ws, size_t ws_size,
                              hipStream_t stream) {
    const float* x  = (const float*)d_in[0];
    const float* H  = (const float*)d_in[1];
    const float* w  = (const float*)d_in[2];
    const float* Wl = (const float*)d_in[3];
    const float* bl = (const float*)d_in[4];
    float* out = (float*)d_out;

    // workspace layout (~34.3 MB):
    // z[N*64] | t[M*64] | Dv[N] | De_cnt[M] | scnt[256] | rowcnt[512]
    // | rowlist[512*ROWCAP] | collist[256*COLCAP]
    float* z        = (float*)d_ws;
    float* t        = z + (size_t)N_NODES * OUT_F;
    float* Dv_raw   = t + (size_t)M_EDGES * OUT_F;
    unsigned* De_cnt  = (unsigned*)(Dv_raw + N_NODES);
    unsigned* scnt    = De_cnt + M_EDGES;
    unsigned* rowcnt  = scnt + NSTR;
    unsigned* rowlist = rowcnt + NBLK;
    unsigned* collist = rowlist + (size_t)NBLK * ROWCAP;

    hipMemsetAsync(t, 0, (size_t)M_EDGES * OUT_F * sizeof(float), stream);
    hipMemsetAsync(De_cnt, 0, M_EDGES * sizeof(unsigned), stream);
    hipMemsetAsync(scnt, 0, NSTR * sizeof(unsigned), stream);

    k_scan   <<<dim3(NBLK),       dim3(512), 0, stream>>>(H, w, Dv_raw, rowlist, rowcnt, collist, scnt);
    k_lin    <<<dim3(N_NODES / 4), dim3(256), 0, stream>>>(x, Wl, bl, Dv_raw, z);
    k_edge_sp<<<dim3(NSTR, 4),    dim3(512), 0, stream>>>(collist, scnt, z, t, De_cnt);
    k_node_sp<<<dim3(NBLK),       dim3(512), 0, stream>>>(rowlist, rowcnt, t, w, De_cnt, Dv_raw, out);
}

// Round 3
// 2754.330 us; speedup vs baseline: 2.3573x; 2.3573x over previous
//
#include <hip/hip_runtime.h>

#define N_NODES 32768
#define M_EDGES 8192
#define IN_DIM  256
#define OUT_F   64

#define SCAN_ROWS 16                  // rows per scan/out block
#define NBLK   (N_NODES / SCAN_ROWS)  // 2048 blocks
#define ROWCAP 1792                   // per-block nz cap (mean 1311, +13 sigma)
#define RBCAP  192                    // per-row nz cap (mean 82, +12 sigma)

// ---------------------------------------------------------------------------
// Pass 1: y[n,k] = x[n,:] @ W[:,k] + b[k]   (NO dvis scaling -> no Dv dep)
// ---------------------------------------------------------------------------
__global__ __launch_bounds__(256) void k_lin(const float* __restrict__ x,
                                             const float* __restrict__ Wl,
                                             const float* __restrict__ b,
                                             float* __restrict__ y) {
    __shared__ float x_s[4 * IN_DIM];
    int tid = threadIdx.x;
    int n0 = blockIdx.x * 4;
    for (int i = 0; i < 4; ++i)
        x_s[i * IN_DIM + tid] = x[(size_t)(n0 + i) * IN_DIM + tid];
    __syncthreads();
    int r = tid >> 6;
    int k = tid & 63;
    float acc = b[k];
    const float* xr = x_s + r * IN_DIM;
    #pragma unroll 8
    for (int i = 0; i < IN_DIM; ++i)
        acc = fmaf(xr[i], Wl[i * OUT_F + k], acc);
    y[(size_t)(n0 + r) * OUT_F + k] = acc;
}

// ---------------------------------------------------------------------------
// Pass 2: THE single H read (1.07 GB). Block = 16 rows x 8192 cols, 256 thr
// (4 waves, wave owns whole rows). Wave-private compaction: cnt is wave-
// uniform (ballot+popc, no atomics). Per finished row: Dv[n] (sparse w-sum),
// fused t scatter t[m,:] += dvis*y[n,:] (fire-and-forget atomics, no return),
// De counts, and coalesced rowlist dump for pass 4.
// ---------------------------------------------------------------------------
__global__ __launch_bounds__(256) void k_scan(const float* __restrict__ H,
                                              const float* __restrict__ w,
                                              const float* __restrict__ y,
                                              float* __restrict__ Dv_raw,
                                              float* __restrict__ t,
                                              unsigned* __restrict__ De_cnt,
                                              unsigned* __restrict__ rowlist,
                                              unsigned* __restrict__ rowcnt) {
    __shared__ unsigned short buf_s[4][RBCAP];
    __shared__ unsigned qc;
    int tid  = threadIdx.x;
    int lane = tid & 63;
    int wid  = tid >> 6;
    if (tid == 0) qc = 0;
    __syncthreads();
    int row0 = blockIdx.x * SCAN_ROWS;
    unsigned* rl = rowlist + (size_t)blockIdx.x * ROWCAP;
    unsigned short* buf = buf_s[wid];
    unsigned long long lt_mask = (1ull << lane) - 1ull;

    for (int rr = wid; rr < SCAN_ROWS; rr += 4) {
        int n = row0 + rr;
        const float4* Hrow = (const float4*)(H + (size_t)n * M_EDGES);
        unsigned cnt = 0;
        for (int jb = 0; jb < M_EDGES / 4; jb += 256) {
            float4 h0 = Hrow[jb + lane];
            float4 h1 = Hrow[jb + 64  + lane];
            float4 h2 = Hrow[jb + 128 + lane];
            float4 h3 = Hrow[jb + 192 + lane];
            #define COMP(v, m)                                                 \
            {                                                                  \
                unsigned long long mk = __ballot((v) != 0.f);                  \
                if (mk) {                                                      \
                    if ((v) != 0.f) {                                          \
                        unsigned pos = cnt + (unsigned)__popcll(mk & lt_mask); \
                        if (pos < RBCAP) buf[pos] = (unsigned short)(m);       \
                    }                                                          \
                    cnt += (unsigned)__popcll(mk);                             \
                }                                                              \
            }
            #define PROC(hv, j4)                                               \
                COMP(hv.x, 4*(j4))   COMP(hv.y, 4*(j4)+1)                      \
                COMP(hv.z, 4*(j4)+2) COMP(hv.w, 4*(j4)+3)
            PROC(h0, jb + lane)
            PROC(h1, jb + 64  + lane)
            PROC(h2, jb + 128 + lane)
            PROC(h3, jb + 192 + lane)
            #undef PROC
            #undef COMP
        }
        if (cnt > RBCAP) cnt = RBCAP;   // never in practice (+12 sigma)

        // Dv[n] = sum of w over this row's nonzeros (sparse gather)
        float dv = 0.f;
        for (unsigned j = lane; j < cnt; j += 64) dv += w[buf[j]];
        for (int off = 32; off; off >>= 1) dv += __shfl_down(dv, off, 64);
        dv = __shfl(dv, 0, 64);
        if (lane == 0) Dv_raw[n] = dv;
        float dvis = rsqrtf(fmaxf(dv, 1e-6f));
        float yv = y[(size_t)n * OUT_F + lane] * dvis;

        // fused H^T scatter: fire-and-forget atomics, coalesced 256B per edge
        #pragma unroll 4
        for (unsigned j = 0; j < cnt; ++j) {
            int m = buf[j];                                   // uniform LDS read
            atomicAdd(&t[(size_t)m * OUT_F + lane], yv);
        }
        // De counts (scattered per-lane atomics, ~2 iters)
        for (unsigned j = lane; j < cnt; j += 64)
            atomicAdd(&De_cnt[buf[j]], 1u);

        // dump row's nz to block bucket (coalesced)
        int base_i = 0;
        if (lane == 0) base_i = (int)atomicAdd(&qc, cnt);
        unsigned base = (unsigned)__shfl(base_i, 0, 64);
        for (unsigned j = lane; j < cnt; j += 64)
            if (base + j < ROWCAP)
                rl[base + j] = ((unsigned)rr << 13) | (unsigned)buf[j];
    }
    __syncthreads();
    if (tid == 0) rowcnt[blockIdx.x] = (qc < (unsigned)ROWCAP) ? qc : (unsigned)ROWCAP;
}

// ---------------------------------------------------------------------------
// Pass 3: t[m,k] *= w[m] / max(De[m], 1)
// ---------------------------------------------------------------------------
__global__ __launch_bounds__(256) void k_scale(float* __restrict__ t,
                                               const float* __restrict__ w,
                                               const unsigned* __restrict__ De_cnt) {
    int idx = blockIdx.x * 256 + threadIdx.x;
    int m = idx >> 6;
    float s = w[m] / fmaxf((float)De_cnt[m], 1.0f);
    t[idx] *= s;
}

// ---------------------------------------------------------------------------
// Pass 4: out[n,:] = dvis[n] * sum_{m in row n} t'[m,:]
// Row-bucketed list (1:1 with scan blocks); t' reads are coalesced 256B
// L2/L3-resident lines; LDS accumulation (2 lanes/bank = free).
// ---------------------------------------------------------------------------
__global__ __launch_bounds__(256) void k_out(const unsigned* __restrict__ rowlist,
                                             const unsigned* __restrict__ rowcnt,
                                             const float* __restrict__ t,
                                             const float* __restrict__ Dv_raw,
                                             float* __restrict__ out) {
    __shared__ float o_s[SCAN_ROWS * OUT_F];   // 4 KB
    int tid  = threadIdx.x;
    int lane = tid & 63;
    int wid  = tid >> 6;
    int b = blockIdx.x;
    unsigned cnt = rowcnt[b];
    for (int i = tid; i < SCAN_ROWS * OUT_F; i += 256) o_s[i] = 0.f;
    __syncthreads();

    const unsigned* rl = rowlist + (size_t)b * ROWCAP;
    for (unsigned base = (unsigned)wid * 64u; base < cnt; base += 256u) {
        unsigned rem = cnt - base; if (rem > 64u) rem = 64u;
        unsigned e = (lane < (int)rem) ? rl[base + lane] : 0u;   // coalesced batch
        #pragma unroll 4
        for (unsigned j = 0; j < rem; ++j) {
            unsigned ej = (unsigned)__shfl((int)e, (int)j, 64);
            int r = (int)(ej >> 13);
            int m = (int)(ej & (M_EDGES - 1u));
            float v = t[(size_t)m * OUT_F + lane];
            atomicAdd(&o_s[r * OUT_F + lane], v);
        }
    }
    __syncthreads();
    int n0 = b * SCAN_ROWS;
    for (int i = tid; i < SCAN_ROWS * OUT_F; i += 256) {
        int r = i >> 6;
        float dvis = rsqrtf(fmaxf(Dv_raw[n0 + r], 1e-6f));
        out[(size_t)n0 * OUT_F + i] = dvis * o_s[i];
    }
}

// ---------------------------------------------------------------------------
extern "C" void kernel_launch(void* const* d_in, const int* in_sizes, int n_in,
                              void* d_out, int out_size, void* d_ws, size_t ws_size,
                              hipStream_t stream) {
    const float* x  = (const float*)d_in[0];
    const float* H  = (const float*)d_in[1];
    const float* w  = (const float*)d_in[2];
    const float* Wl = (const float*)d_in[3];
    const float* bl = (const float*)d_in[4];
    float* out = (float*)d_out;

    // workspace (~25 MB): y[N*64] | t[M*64] | Dv[N] | De[M] | rowcnt[NBLK] | rowlist
    float* y        = (float*)d_ws;
    float* t        = y + (size_t)N_NODES * OUT_F;
    float* Dv_raw   = t + (size_t)M_EDGES * OUT_F;
    unsigned* De_cnt  = (unsigned*)(Dv_raw + N_NODES);
    unsigned* rowcnt  = De_cnt + M_EDGES;
    unsigned* rowlist = rowcnt + NBLK;

    hipMemsetAsync(t, 0, (size_t)M_EDGES * OUT_F * sizeof(float), stream);
    hipMemsetAsync(De_cnt, 0, M_EDGES * sizeof(unsigned), stream);

    k_lin  <<<dim3(N_NODES / 4),          dim3(256), 0, stream>>>(x, Wl, bl, y);
    k_scan <<<dim3(NBLK),                 dim3(256), 0, stream>>>(H, w, y, Dv_raw, t, De_cnt, rowlist, rowcnt);
    k_scale<<<dim3(M_EDGES * OUT_F / 256),dim3(256), 0, stream>>>(t, w, De_cnt);
    k_out  <<<dim3(NBLK),                 dim3(256), 0, stream>>>(rowlist, rowcnt, t, Dv_raw, out);
}

// Round 4
// 1972.408 us; speedup vs baseline: 3.2918x; 1.3964x over previous
//
#include <hip/hip_runtime.h>

#define N_NODES 32768
#define M_EDGES 8192
#define IN_DIM  256
#define OUT_F   64

#define SCAN_ROWS 16                  // rows per scan block
#define NBLK   (N_NODES / SCAN_ROWS)  // 2048 scan blocks
#define RBCAP  192                    // per-row nz cap (mean 82, sd ~9 -> +12 sigma)

// ---------------------------------------------------------------------------
// Pass 1: y[n,k] = x[n,:] @ W[:,k] + b[k]   (no Dv dependency)
// ---------------------------------------------------------------------------
__global__ __launch_bounds__(256) void k_lin(const float* __restrict__ x,
                                             const float* __restrict__ Wl,
                                             const float* __restrict__ b,
                                             float* __restrict__ y) {
    __shared__ float x_s[4 * IN_DIM];
    int tid = threadIdx.x;
    int n0 = blockIdx.x * 4;
    for (int i = 0; i < 4; ++i)
        x_s[i * IN_DIM + tid] = x[(size_t)(n0 + i) * IN_DIM + tid];
    __syncthreads();
    int r = tid >> 6;
    int k = tid & 63;
    float acc = b[k];
    const float* xr = x_s + r * IN_DIM;
    #pragma unroll 8
    for (int i = 0; i < IN_DIM; ++i)
        acc = fmaf(xr[i], Wl[i * OUT_F + k], acc);
    y[(size_t)(n0 + r) * OUT_F + k] = acc;
}

// ---------------------------------------------------------------------------
// Pass 2: the single full H read (1.07 GB). Pure scan + compact, NO scatter.
// Wave owns whole rows. Produces fixed-stride CSR (rowidx ushort / rowlen),
// Dv[n] (sparse w-gather), De counts (fire-and-forget per-lane atomics).
// ---------------------------------------------------------------------------
__global__ __launch_bounds__(256) void k_scan(const float* __restrict__ H,
                                              const float* __restrict__ w,
                                              float* __restrict__ Dv_raw,
                                              unsigned short* __restrict__ rowidx,
                                              unsigned* __restrict__ rowlen,
                                              unsigned* __restrict__ De_cnt) {
    __shared__ unsigned short buf_s[4][RBCAP];
    int tid  = threadIdx.x;
    int lane = tid & 63;
    int wid  = tid >> 6;
    int row0 = blockIdx.x * SCAN_ROWS;
    unsigned short* buf = buf_s[wid];
    unsigned long long lt_mask = (1ull << lane) - 1ull;

    for (int rr = wid; rr < SCAN_ROWS; rr += 4) {
        int n = row0 + rr;
        const float4* Hrow = (const float4*)(H + (size_t)n * M_EDGES);
        unsigned cnt = 0;
        for (int jb = 0; jb < M_EDGES / 4; jb += 256) {
            float4 h0 = Hrow[jb + lane];
            float4 h1 = Hrow[jb + 64  + lane];
            float4 h2 = Hrow[jb + 128 + lane];
            float4 h3 = Hrow[jb + 192 + lane];
            #define COMP(v, m)                                                 \
            {                                                                  \
                unsigned long long mk = __ballot((v) != 0.f);                  \
                if (mk) {                                                      \
                    if ((v) != 0.f) {                                          \
                        unsigned pos = cnt + (unsigned)__popcll(mk & lt_mask); \
                        if (pos < RBCAP) buf[pos] = (unsigned short)(m);       \
                    }                                                          \
                    cnt += (unsigned)__popcll(mk);                             \
                }                                                              \
            }
            #define PROC(hv, j4)                                               \
                COMP(hv.x, 4*(j4))   COMP(hv.y, 4*(j4)+1)                      \
                COMP(hv.z, 4*(j4)+2) COMP(hv.w, 4*(j4)+3)
            PROC(h0, jb + lane)
            PROC(h1, jb + 64  + lane)
            PROC(h2, jb + 128 + lane)
            PROC(h3, jb + 192 + lane)
            #undef PROC
            #undef COMP
        }
        if (cnt > RBCAP) cnt = RBCAP;

        // Dv[n] = sum of w over row nonzeros
        float dv = 0.f;
        for (unsigned j = lane; j < cnt; j += 64) dv += w[buf[j]];
        for (int off = 32; off; off >>= 1) dv += __shfl_down(dv, off, 64);
        if (lane == 0) { Dv_raw[n] = dv; rowlen[n] = cnt; }

        // De counts (scattered fire-and-forget, ~2 wave-iters)
        for (unsigned j = lane; j < cnt; j += 64)
            atomicAdd(&De_cnt[buf[j]], 1u);

        // dump CSR row (coalesced-ish 2B stores)
        for (unsigned j = lane; j < cnt; j += 64)
            rowidx[(size_t)n * RBCAP + j] = buf[j];
    }
}

// ---------------------------------------------------------------------------
// Pass 3: t[m,:] += dvis[n] * y[n,:] for each nz (n,m).  One wave per row.
// Indices -> SGPR via readfirstlane; fire-and-forget global atomics (no
// return, no wait). val[lane] held in a register.
// ---------------------------------------------------------------------------
__global__ __launch_bounds__(256) void k_edge(const unsigned short* __restrict__ rowidx,
                                              const unsigned* __restrict__ rowlen,
                                              const float* __restrict__ Dv_raw,
                                              const float* __restrict__ y,
                                              float* __restrict__ t) {
    int lane = threadIdx.x & 63;
    int wid  = threadIdx.x >> 6;
    int n = blockIdx.x * 4 + wid;
    unsigned cnt = rowlen[n];
    float dvis = rsqrtf(fmaxf(Dv_raw[n], 1e-6f));
    float val = y[(size_t)n * OUT_F + lane] * dvis;
    const uint4* rp = (const uint4*)(rowidx + (size_t)n * RBCAP);
    unsigned g8 = cnt >> 3;
    for (unsigned g = 0; g < g8; ++g) {
        uint4 pk = rp[g];
        unsigned a = (unsigned)__builtin_amdgcn_readfirstlane((int)pk.x);
        unsigned b = (unsigned)__builtin_amdgcn_readfirstlane((int)pk.y);
        unsigned c = (unsigned)__builtin_amdgcn_readfirstlane((int)pk.z);
        unsigned d = (unsigned)__builtin_amdgcn_readfirstlane((int)pk.w);
        atomicAdd(&t[(size_t)(a & 0xffffu) * OUT_F + lane], val);
        atomicAdd(&t[(size_t)(a >> 16)     * OUT_F + lane], val);
        atomicAdd(&t[(size_t)(b & 0xffffu) * OUT_F + lane], val);
        atomicAdd(&t[(size_t)(b >> 16)     * OUT_F + lane], val);
        atomicAdd(&t[(size_t)(c & 0xffffu) * OUT_F + lane], val);
        atomicAdd(&t[(size_t)(c >> 16)     * OUT_F + lane], val);
        atomicAdd(&t[(size_t)(d & 0xffffu) * OUT_F + lane], val);
        atomicAdd(&t[(size_t)(d >> 16)     * OUT_F + lane], val);
    }
    for (unsigned j = g8 * 8; j < cnt; ++j) {
        int m = __builtin_amdgcn_readfirstlane((int)rowidx[(size_t)n * RBCAP + j]);
        atomicAdd(&t[(size_t)m * OUT_F + lane], val);
    }
}

// ---------------------------------------------------------------------------
// Pass 4: t[m,k] *= w[m] / max(De[m], 1)
// ---------------------------------------------------------------------------
__global__ __launch_bounds__(256) void k_scale(float* __restrict__ t,
                                               const float* __restrict__ w,
                                               const unsigned* __restrict__ De_cnt) {
    int idx = blockIdx.x * 256 + threadIdx.x;
    int m = idx >> 6;
    float s = w[m] / fmaxf((float)De_cnt[m], 1.0f);
    t[idx] *= s;
}

// ---------------------------------------------------------------------------
// Pass 5: out[n,:] = dvis[n] * sum_{m in row n} t'[m,:].  One wave per row.
// SGPR indices, plain VGPR accumulation, 8 L2-resident loads in flight.
// ---------------------------------------------------------------------------
__global__ __launch_bounds__(256) void k_out(const unsigned short* __restrict__ rowidx,
                                             const unsigned* __restrict__ rowlen,
                                             const float* __restrict__ t,
                                             const float* __restrict__ Dv_raw,
                                             float* __restrict__ out) {
    int lane = threadIdx.x & 63;
    int wid  = threadIdx.x >> 6;
    int n = blockIdx.x * 4 + wid;
    unsigned cnt = rowlen[n];
    const uint4* rp = (const uint4*)(rowidx + (size_t)n * RBCAP);
    float a0 = 0.f, a1 = 0.f, a2 = 0.f, a3 = 0.f;
    float a4 = 0.f, a5 = 0.f, a6 = 0.f, a7 = 0.f;
    unsigned g8 = cnt >> 3;
    for (unsigned g = 0; g < g8; ++g) {
        uint4 pk = rp[g];
        unsigned a = (unsigned)__builtin_amdgcn_readfirstlane((int)pk.x);
        unsigned b = (unsigned)__builtin_amdgcn_readfirstlane((int)pk.y);
        unsigned c = (unsigned)__builtin_amdgcn_readfirstlane((int)pk.z);
        unsigned d = (unsigned)__builtin_amdgcn_readfirstlane((int)pk.w);
        a0 += t[(size_t)(a & 0xffffu) * OUT_F + lane];
        a1 += t[(size_t)(a >> 16)     * OUT_F + lane];
        a2 += t[(size_t)(b & 0xffffu) * OUT_F + lane];
        a3 += t[(size_t)(b >> 16)     * OUT_F + lane];
        a4 += t[(size_t)(c & 0xffffu) * OUT_F + lane];
        a5 += t[(size_t)(c >> 16)     * OUT_F + lane];
        a6 += t[(size_t)(d & 0xffffu) * OUT_F + lane];
        a7 += t[(size_t)(d >> 16)     * OUT_F + lane];
    }
    float acc = ((a0 + a1) + (a2 + a3)) + ((a4 + a5) + (a6 + a7));
    for (unsigned j = g8 * 8; j < cnt; ++j) {
        int m = __builtin_amdgcn_readfirstlane((int)rowidx[(size_t)n * RBCAP + j]);
        acc += t[(size_t)m * OUT_F + lane];
    }
    float dvis = rsqrtf(fmaxf(Dv_raw[n], 1e-6f));
    out[(size_t)n * OUT_F + lane] = dvis * acc;
}

// ---------------------------------------------------------------------------
extern "C" void kernel_launch(void* const* d_in, const int* in_sizes, int n_in,
                              void* d_out, int out_size, void* d_ws, size_t ws_size,
                              hipStream_t stream) {
    const float* x  = (const float*)d_in[0];
    const float* H  = (const float*)d_in[1];
    const float* w  = (const float*)d_in[2];
    const float* Wl = (const float*)d_in[3];
    const float* bl = (const float*)d_in[4];
    float* out = (float*)d_out;

    // workspace (~23.4 MB):
    // y[N*64] | t[M*64] | Dv[N] | De[M] | rowlen[N] | rowidx[N*RBCAP] (ushort)
    float* y        = (float*)d_ws;
    float* t        = y + (size_t)N_NODES * OUT_F;
    float* Dv_raw   = t + (size_t)M_EDGES * OUT_F;
    unsigned* De_cnt  = (unsigned*)(Dv_raw + N_NODES);
    unsigned* rowlen  = De_cnt + M_EDGES;
    unsigned short* rowidx = (unsigned short*)(rowlen + N_NODES);

    hipMemsetAsync(t, 0, (size_t)M_EDGES * OUT_F * sizeof(float), stream);
    hipMemsetAsync(De_cnt, 0, M_EDGES * sizeof(unsigned), stream);

    k_lin  <<<dim3(N_NODES / 4),           dim3(256), 0, stream>>>(x, Wl, bl, y);
    k_scan <<<dim3(NBLK),                  dim3(256), 0, stream>>>(H, w, Dv_raw, rowidx, rowlen, De_cnt);
    k_edge <<<dim3(N_NODES / 4),           dim3(256), 0, stream>>>(rowidx, rowlen, Dv_raw, y, t);
    k_scale<<<dim3(M_EDGES * OUT_F / 256), dim3(256), 0, stream>>>(t, w, De_cnt);
    k_out  <<<dim3(N_NODES / 4),           dim3(256), 0, stream>>>(rowidx, rowlen, t, Dv_raw, out);
}

// Round 5
// 1621.181 us; speedup vs baseline: 4.0050x; 1.2166x over previous
//
#include <hip/hip_runtime.h>

#define N_NODES 32768
#define M_EDGES 8192
#define IN_DIM  256
#define OUT_F   64

#define SCAN_ROWS 16                  // rows per scan block
#define NBLK   (N_NODES / SCAN_ROWS)  // 2048 scan blocks
#define RBCAP  192                    // per-row nz cap (mean 82, +12 sigma)
#define COLCAP 512                    // per-edge node cap (mean 328, +10 sigma)

// ---------------------------------------------------------------------------
// Pass 1: the single full H read (1.07 GB). PURE scan+compact: ballot prefix,
// direct 2B global stores into fixed-stride CSR. No LDS, no gathers, no
// atomics — nothing in the hot loop but coalesced loads and cheap VALU.
// ---------------------------------------------------------------------------
__global__ __launch_bounds__(256) void k_scan(const float* __restrict__ H,
                                              unsigned short* __restrict__ rowidx,
                                              unsigned* __restrict__ rowlen) {
    int tid  = threadIdx.x;
    int lane = tid & 63;
    int wid  = tid >> 6;
    int row0 = blockIdx.x * SCAN_ROWS;
    unsigned long long lt = (1ull << lane) - 1ull;

    for (int rr = wid; rr < SCAN_ROWS; rr += 4) {
        int n = row0 + rr;
        const float4* Hrow = (const float4*)(H + (size_t)n * M_EDGES);
        unsigned short* out_r = rowidx + (size_t)n * RBCAP;
        unsigned cnt = 0;
        for (int jb = 0; jb < M_EDGES / 4; jb += 256) {
            float4 h0 = Hrow[jb + lane];
            float4 h1 = Hrow[jb + 64  + lane];
            float4 h2 = Hrow[jb + 128 + lane];
            float4 h3 = Hrow[jb + 192 + lane];
            #define COMP(v, mexp)                                              \
            {                                                                  \
                unsigned long long mk = __ballot((v) != 0.f);                  \
                if (mk) {                                                      \
                    if ((v) != 0.f) {                                          \
                        unsigned pos = cnt + (unsigned)__popcll(mk & lt);      \
                        if (pos < RBCAP) out_r[pos] = (unsigned short)(mexp);  \
                    }                                                          \
                    cnt += (unsigned)__popcll(mk);                             \
                }                                                              \
            }
            #define PROC(hv, j4)                                               \
                COMP(hv.x, 4*(j4))   COMP(hv.y, 4*(j4)+1)                      \
                COMP(hv.z, 4*(j4)+2) COMP(hv.w, 4*(j4)+3)
            PROC(h0, jb + lane)
            PROC(h1, jb + 64  + lane)
            PROC(h2, jb + 128 + lane)
            PROC(h3, jb + 192 + lane)
            #undef PROC
            #undef COMP
        }
        if (lane == 0) rowlen[n] = (cnt < (unsigned)RBCAP) ? cnt : (unsigned)RBCAP;
    }
}

// ---------------------------------------------------------------------------
// Pass 2: CSR -> fixed-stride CSC (edge -> node list) + Dv.  Per-lane
// independent returning atomics (64 in flight per wave, 8192 counters —
// throughput-bound, not chained). Also computes Dv[n] = sum w over row nz.
// ---------------------------------------------------------------------------
__global__ __launch_bounds__(256) void k_csc(const unsigned short* __restrict__ rowidx,
                                             const unsigned* __restrict__ rowlen,
                                             const float* __restrict__ w,
                                             unsigned short* __restrict__ cscidx,
                                             unsigned* __restrict__ cscfill,
                                             float* __restrict__ Dv_raw) {
    int lane = threadIdx.x & 63;
    int wid  = threadIdx.x >> 6;
    int n = blockIdx.x * 4 + wid;
    unsigned cnt = rowlen[n];
    float dv = 0.f;
    for (unsigned j = lane; j < cnt; j += 64) {
        int m = rowidx[(size_t)n * RBCAP + j];
        dv += w[m];
        unsigned p = atomicAdd(&cscfill[m], 1u);
        if (p < (unsigned)COLCAP)
            cscidx[(size_t)m * COLCAP + p] = (unsigned short)n;
    }
    for (int off = 32; off; off >>= 1) dv += __shfl_down(dv, off, 64);
    if (lane == 0) Dv_raw[n] = dv;
}

// ---------------------------------------------------------------------------
// Pass 3: y2[n,k] = rsqrt(max(Dv[n],1e-6)) * (x[n,:] @ W[:,k] + b[k])
// 16 rows per block for 4x W-reuse from L1.
// ---------------------------------------------------------------------------
__global__ __launch_bounds__(256) void k_lin(const float* __restrict__ x,
                                             const float* __restrict__ Wl,
                                             const float* __restrict__ b,
                                             const float* __restrict__ Dv_raw,
                                             float* __restrict__ y2) {
    __shared__ float x_s[16 * IN_DIM];   // 16 KB
    int tid = threadIdx.x;
    int n0 = blockIdx.x * 16;
    for (int i = tid; i < 16 * IN_DIM; i += 256)
        x_s[i] = x[(size_t)n0 * IN_DIM + i];
    __syncthreads();
    int k = tid & 63;
    int rbase = tid >> 6;
    for (int pass = 0; pass < 4; ++pass) {
        int r = pass * 4 + rbase;
        float acc = b[k];
        const float* xr = x_s + r * IN_DIM;
        #pragma unroll 8
        for (int i = 0; i < IN_DIM; ++i)
            acc = fmaf(xr[i], Wl[i * OUT_F + k], acc);
        float dvis = rsqrtf(fmaxf(Dv_raw[n0 + r], 1e-6f));
        y2[(size_t)(n0 + r) * OUT_F + k] = acc * dvis;
    }
}

// ---------------------------------------------------------------------------
// Pass 4: t'[m,:] = (w[m]/max(De[m],1)) * sum_{n in edge m} y2[n,:]
// Pure gather, one wave per edge. SGPR-broadcast indices, 8 loads in flight,
// no atomics. De[m] = cscfill[m] (true count). Writes t' directly (no memset,
// no k_scale).
// ---------------------------------------------------------------------------
__global__ __launch_bounds__(256) void k_edge(const unsigned short* __restrict__ cscidx,
                                              const unsigned* __restrict__ cscfill,
                                              const float* __restrict__ w,
                                              const float* __restrict__ y2,
                                              float* __restrict__ t) {
    int lane = threadIdx.x & 63;
    int wid  = threadIdx.x >> 6;
    int m = blockIdx.x * 4 + wid;
    unsigned de = cscfill[m];
    unsigned cnt = (de < (unsigned)COLCAP) ? de : (unsigned)COLCAP;
    const uint4* cp = (const uint4*)(cscidx + (size_t)m * COLCAP);
    float a0 = 0.f, a1 = 0.f, a2 = 0.f, a3 = 0.f;
    float a4 = 0.f, a5 = 0.f, a6 = 0.f, a7 = 0.f;
    unsigned g8 = cnt >> 3;
    for (unsigned g = 0; g < g8; ++g) {
        uint4 pk = cp[g];
        unsigned A = (unsigned)__builtin_amdgcn_readfirstlane((int)pk.x);
        unsigned B = (unsigned)__builtin_amdgcn_readfirstlane((int)pk.y);
        unsigned C = (unsigned)__builtin_amdgcn_readfirstlane((int)pk.z);
        unsigned D = (unsigned)__builtin_amdgcn_readfirstlane((int)pk.w);
        a0 += y2[(size_t)(A & 0xffffu) * OUT_F + lane];
        a1 += y2[(size_t)(A >> 16)     * OUT_F + lane];
        a2 += y2[(size_t)(B & 0xffffu) * OUT_F + lane];
        a3 += y2[(size_t)(B >> 16)     * OUT_F + lane];
        a4 += y2[(size_t)(C & 0xffffu) * OUT_F + lane];
        a5 += y2[(size_t)(C >> 16)     * OUT_F + lane];
        a6 += y2[(size_t)(D & 0xffffu) * OUT_F + lane];
        a7 += y2[(size_t)(D >> 16)     * OUT_F + lane];
    }
    float acc = ((a0 + a1) + (a2 + a3)) + ((a4 + a5) + (a6 + a7));
    for (unsigned j = g8 * 8; j < cnt; ++j) {
        int n = __builtin_amdgcn_readfirstlane((int)cscidx[(size_t)m * COLCAP + j]);
        acc += y2[(size_t)n * OUT_F + lane];
    }
    float sc = w[m] / fmaxf((float)de, 1.0f);
    t[(size_t)m * OUT_F + lane] = acc * sc;
}

// ---------------------------------------------------------------------------
// Pass 5: out[n,:] = dvis[n] * sum_{m in row n} t'[m,:].  One wave per row,
// SGPR indices, 8 L2-resident loads in flight, no atomics.
// ---------------------------------------------------------------------------
__global__ __launch_bounds__(256) void k_out(const unsigned short* __restrict__ rowidx,
                                             const unsigned* __restrict__ rowlen,
                                             const float* __restrict__ t,
                                             const float* __restrict__ Dv_raw,
                                             float* __restrict__ out) {
    int lane = threadIdx.x & 63;
    int wid  = threadIdx.x >> 6;
    int n = blockIdx.x * 4 + wid;
    unsigned cnt = rowlen[n];
    const uint4* rp = (const uint4*)(rowidx + (size_t)n * RBCAP);
    float a0 = 0.f, a1 = 0.f, a2 = 0.f, a3 = 0.f;
    float a4 = 0.f, a5 = 0.f, a6 = 0.f, a7 = 0.f;
    unsigned g8 = cnt >> 3;
    for (unsigned g = 0; g < g8; ++g) {
        uint4 pk = rp[g];
        unsigned A = (unsigned)__builtin_amdgcn_readfirstlane((int)pk.x);
        unsigned B = (unsigned)__builtin_amdgcn_readfirstlane((int)pk.y);
        unsigned C = (unsigned)__builtin_amdgcn_readfirstlane((int)pk.z);
        unsigned D = (unsigned)__builtin_amdgcn_readfirstlane((int)pk.w);
        a0 += t[(size_t)(A & 0xffffu) * OUT_F + lane];
        a1 += t[(size_t)(A >> 16)     * OUT_F + lane];
        a2 += t[(size_t)(B & 0xffffu) * OUT_F + lane];
        a3 += t[(size_t)(B >> 16)     * OUT_F + lane];
        a4 += t[(size_t)(C & 0xffffu) * OUT_F + lane];
        a5 += t[(size_t)(C >> 16)     * OUT_F + lane];
        a6 += t[(size_t)(D & 0xffffu) * OUT_F + lane];
        a7 += t[(size_t)(D >> 16)     * OUT_F + lane];
    }
    float acc = ((a0 + a1) + (a2 + a3)) + ((a4 + a5) + (a6 + a7));
    for (unsigned j = g8 * 8; j < cnt; ++j) {
        int m = __builtin_amdgcn_readfirstlane((int)rowidx[(size_t)n * RBCAP + j]);
        acc += t[(size_t)m * OUT_F + lane];
    }
    float dvis = rsqrtf(fmaxf(Dv_raw[n], 1e-6f));
    out[(size_t)n * OUT_F + lane] = dvis * acc;
}

// ---------------------------------------------------------------------------
extern "C" void kernel_launch(void* const* d_in, const int* in_sizes, int n_in,
                              void* d_out, int out_size, void* d_ws, size_t ws_size,
                              hipStream_t stream) {
    const float* x  = (const float*)d_in[0];
    const float* H  = (const float*)d_in[1];
    const float* w  = (const float*)d_in[2];
    const float* Wl = (const float*)d_in[3];
    const float* bl = (const float*)d_in[4];
    float* out = (float*)d_out;

    // workspace (~31.7 MB):
    // y2[N*64] | t[M*64] | Dv[N] | rowlen[N] | cscfill[M]
    // | rowidx[N*RBCAP] ushort | cscidx[M*COLCAP] ushort
    float*    y2      = (float*)d_ws;
    float*    t       = y2 + (size_t)N_NODES * OUT_F;
    float*    Dv_raw  = t + (size_t)M_EDGES * OUT_F;
    unsigned* rowlen  = (unsigned*)(Dv_raw + N_NODES);
    unsigned* cscfill = rowlen + N_NODES;
    unsigned short* rowidx = (unsigned short*)(cscfill + M_EDGES);
    unsigned short* cscidx = rowidx + (size_t)N_NODES * RBCAP;

    hipMemsetAsync(cscfill, 0, M_EDGES * sizeof(unsigned), stream);

    k_scan<<<dim3(NBLK),         dim3(256), 0, stream>>>(H, rowidx, rowlen);
    k_csc <<<dim3(N_NODES / 4),  dim3(256), 0, stream>>>(rowidx, rowlen, w, cscidx, cscfill, Dv_raw);
    k_lin <<<dim3(N_NODES / 16), dim3(256), 0, stream>>>(x, Wl, bl, Dv_raw, y2);
    k_edge<<<dim3(M_EDGES / 4),  dim3(256), 0, stream>>>(cscidx, cscfill, w, y2, t);
    k_out <<<dim3(N_NODES / 4),  dim3(256), 0, stream>>>(rowidx, rowlen, t, Dv_raw, out);
}

// Round 6
// 1606.936 us; speedup vs baseline: 4.0405x; 1.0089x over previous
//
#include <hip/hip_runtime.h>

#define N_NODES 32768
#define M_EDGES 8192
#define IN_DIM  256
#define OUT_F   64

#define SCAN_ROWS 16                  // rows per scan block
#define NBLK   (N_NODES / SCAN_ROWS)  // 2048 scan blocks
#define RBCAP  192                    // per-row nz cap (mean 82, +12 sigma)
#define COLCAP 512                    // per-edge node cap (mean 328, +10 sigma)

// ---------------------------------------------------------------------------
// Pass 1: the single full H read (1.07 GB). Pure scan+compact: ballot prefix,
// direct 2B global stores into fixed-stride CSR. 8 loads in flight per wave.
// ---------------------------------------------------------------------------
__global__ __launch_bounds__(256) void k_scan(const float* __restrict__ H,
                                              unsigned short* __restrict__ rowidx,
                                              unsigned* __restrict__ rowlen) {
    int tid  = threadIdx.x;
    int lane = tid & 63;
    int wid  = tid >> 6;
    int row0 = blockIdx.x * SCAN_ROWS;
    unsigned long long lt = (1ull << lane) - 1ull;

    for (int rr = wid; rr < SCAN_ROWS; rr += 4) {
        int n = row0 + rr;
        const float4* Hrow = (const float4*)(H + (size_t)n * M_EDGES);
        unsigned short* out_r = rowidx + (size_t)n * RBCAP;
        unsigned cnt = 0;
        for (int jb = 0; jb < M_EDGES / 4; jb += 512) {   // 8 float4 in flight
            float4 h0 = Hrow[jb + lane];
            float4 h1 = Hrow[jb + 64  + lane];
            float4 h2 = Hrow[jb + 128 + lane];
            float4 h3 = Hrow[jb + 192 + lane];
            float4 h4 = Hrow[jb + 256 + lane];
            float4 h5 = Hrow[jb + 320 + lane];
            float4 h6 = Hrow[jb + 384 + lane];
            float4 h7 = Hrow[jb + 448 + lane];
            #define COMP(v, mexp)                                              \
            {                                                                  \
                unsigned long long mk = __ballot((v) != 0.f);                  \
                if (mk) {                                                      \
                    if ((v) != 0.f) {                                          \
                        unsigned pos = cnt + (unsigned)__popcll(mk & lt);      \
                        if (pos < RBCAP) out_r[pos] = (unsigned short)(mexp);  \
                    }                                                          \
                    cnt += (unsigned)__popcll(mk);                             \
                }                                                              \
            }
            #define PROC(hv, j4)                                               \
                COMP(hv.x, 4*(j4))   COMP(hv.y, 4*(j4)+1)                      \
                COMP(hv.z, 4*(j4)+2) COMP(hv.w, 4*(j4)+3)
            PROC(h0, jb + lane)
            PROC(h1, jb + 64  + lane)
            PROC(h2, jb + 128 + lane)
            PROC(h3, jb + 192 + lane)
            PROC(h4, jb + 256 + lane)
            PROC(h5, jb + 320 + lane)
            PROC(h6, jb + 384 + lane)
            PROC(h7, jb + 448 + lane)
            #undef PROC
            #undef COMP
        }
        if (lane == 0) rowlen[n] = (cnt < (unsigned)RBCAP) ? cnt : (unsigned)RBCAP;
    }
}

// ---------------------------------------------------------------------------
// Pass 2: CSR -> fixed-stride CSC + Dv. Lane-parallel independent returning
// atomics (64 in flight per wave, 8192 counters).
// ---------------------------------------------------------------------------
__global__ __launch_bounds__(256) void k_csc(const unsigned short* __restrict__ rowidx,
                                             const unsigned* __restrict__ rowlen,
                                             const float* __restrict__ w,
                                             unsigned short* __restrict__ cscidx,
                                             unsigned* __restrict__ cscfill,
                                             float* __restrict__ Dv_raw) {
    int lane = threadIdx.x & 63;
    int wid  = threadIdx.x >> 6;
    int n = blockIdx.x * 4 + wid;
    unsigned cnt = rowlen[n];
    float dv = 0.f;
    for (unsigned j = lane; j < cnt; j += 64) {
        int m = rowidx[(size_t)n * RBCAP + j];
        dv += w[m];
        unsigned p = atomicAdd(&cscfill[m], 1u);
        if (p < (unsigned)COLCAP)
            cscidx[(size_t)m * COLCAP + p] = (unsigned short)n;
    }
    for (int off = 32; off; off >>= 1) dv += __shfl_down(dv, off, 64);
    if (lane == 0) Dv_raw[n] = dv;
}

// ---------------------------------------------------------------------------
// Pass 3: y2[n,k] = rsqrt(max(Dv[n],1e-6)) * (x[n,:] @ W[:,k] + b[k])
// ---------------------------------------------------------------------------
__global__ __launch_bounds__(256) void k_lin(const float* __restrict__ x,
                                             const float* __restrict__ Wl,
                                             const float* __restrict__ b,
                                             const float* __restrict__ Dv_raw,
                                             float* __restrict__ y2) {
    __shared__ float x_s[16 * IN_DIM];   // 16 KB
    int tid = threadIdx.x;
    int n0 = blockIdx.x * 16;
    for (int i = tid; i < 16 * IN_DIM; i += 256)
        x_s[i] = x[(size_t)n0 * IN_DIM + i];
    __syncthreads();
    int k = tid & 63;
    int rbase = tid >> 6;
    for (int pass = 0; pass < 4; ++pass) {
        int r = pass * 4 + rbase;
        float acc = b[k];
        const float* xr = x_s + r * IN_DIM;
        #pragma unroll 8
        for (int i = 0; i < IN_DIM; ++i)
            acc = fmaf(xr[i], Wl[i * OUT_F + k], acc);
        float dvis = rsqrtf(fmaxf(Dv_raw[n0 + r], 1e-6f));
        y2[(size_t)(n0 + r) * OUT_F + k] = acc * dvis;
    }
}

// Gather macro: one 64-entry segment held lane-parallel in register `vi`;
// readlane broadcast (no memory dependency), 8 gathers in flight.
#define SEG_GATHER(vi, base, cnt, src, acc0, acc1, acc2, acc3, acc4, acc5, acc6, acc7) \
{                                                                              \
    unsigned end = ((cnt) > (base)) ? ((cnt) - (base)) : 0u;                   \
    if (end > 64u) end = 64u;                                                  \
    unsigned sj = 0;                                                           \
    for (; sj + 8 <= end; sj += 8) {                                           \
        int m0 = __builtin_amdgcn_readlane(vi, sj + 0);                        \
        int m1 = __builtin_amdgcn_readlane(vi, sj + 1);                        \
        int m2 = __builtin_amdgcn_readlane(vi, sj + 2);                        \
        int m3 = __builtin_amdgcn_readlane(vi, sj + 3);                        \
        int m4 = __builtin_amdgcn_readlane(vi, sj + 4);                        \
        int m5 = __builtin_amdgcn_readlane(vi, sj + 5);                        \
        int m6 = __builtin_amdgcn_readlane(vi, sj + 6);                        \
        int m7 = __builtin_amdgcn_readlane(vi, sj + 7);                        \
        acc0 += src[(size_t)m0 * OUT_F + lane];                                \
        acc1 += src[(size_t)m1 * OUT_F + lane];                                \
        acc2 += src[(size_t)m2 * OUT_F + lane];                                \
        acc3 += src[(size_t)m3 * OUT_F + lane];                                \
        acc4 += src[(size_t)m4 * OUT_F + lane];                                \
        acc5 += src[(size_t)m5 * OUT_F + lane];                                \
        acc6 += src[(size_t)m6 * OUT_F + lane];                                \
        acc7 += src[(size_t)m7 * OUT_F + lane];                                \
    }                                                                          \
    for (; sj < end; ++sj) {                                                   \
        int mm = __builtin_amdgcn_readlane(vi, sj);                            \
        acc0 += src[(size_t)mm * OUT_F + lane];                                \
    }                                                                          \
}

// ---------------------------------------------------------------------------
// Pass 4: t'[m,:] = (w[m]/max(De[m],1)) * sum_{n in edge m} y2[n,:]
// All 8 index segments preloaded lane-parallel; pure gather, no atomics.
// ---------------------------------------------------------------------------
__global__ __launch_bounds__(256) void k_edge(const unsigned short* __restrict__ cscidx,
                                              const unsigned* __restrict__ cscfill,
                                              const float* __restrict__ w,
                                              const float* __restrict__ y2,
                                              float* __restrict__ t) {
    int lane = threadIdx.x & 63;
    int wid  = threadIdx.x >> 6;
    int m = blockIdx.x * 4 + wid;
    unsigned de = cscfill[m];
    unsigned cnt = (de < (unsigned)COLCAP) ? de : (unsigned)COLCAP;
    const unsigned short* cp = cscidx + (size_t)m * COLCAP;
    int v0 = cp[lane];         int v1 = cp[64  + lane];
    int v2 = cp[128 + lane];   int v3 = cp[192 + lane];
    int v4 = cp[256 + lane];   int v5 = cp[320 + lane];
    int v6 = cp[384 + lane];   int v7 = cp[448 + lane];
    float a0 = 0.f, a1 = 0.f, a2 = 0.f, a3 = 0.f;
    float a4 = 0.f, a5 = 0.f, a6 = 0.f, a7 = 0.f;
    SEG_GATHER(v0,   0u, cnt, y2, a0, a1, a2, a3, a4, a5, a6, a7)
    SEG_GATHER(v1,  64u, cnt, y2, a0, a1, a2, a3, a4, a5, a6, a7)
    SEG_GATHER(v2, 128u, cnt, y2, a0, a1, a2, a3, a4, a5, a6, a7)
    SEG_GATHER(v3, 192u, cnt, y2, a0, a1, a2, a3, a4, a5, a6, a7)
    SEG_GATHER(v4, 256u, cnt, y2, a0, a1, a2, a3, a4, a5, a6, a7)
    SEG_GATHER(v5, 320u, cnt, y2, a0, a1, a2, a3, a4, a5, a6, a7)
    SEG_GATHER(v6, 384u, cnt, y2, a0, a1, a2, a3, a4, a5, a6, a7)
    SEG_GATHER(v7, 448u, cnt, y2, a0, a1, a2, a3, a4, a5, a6, a7)
    float acc = ((a0 + a1) + (a2 + a3)) + ((a4 + a5) + (a6 + a7));
    float sc = w[m] / fmaxf((float)de, 1.0f);
    t[(size_t)m * OUT_F + lane] = acc * sc;
}

// ---------------------------------------------------------------------------
// Pass 5: out[n,:] = dvis[n] * sum_{m in row n} t'[m,:]
// ---------------------------------------------------------------------------
__global__ __launch_bounds__(256) void k_out(const unsigned short* __restrict__ rowidx,
                                             const unsigned* __restrict__ rowlen,
                                             const float* __restrict__ t,
                                             const float* __restrict__ Dv_raw,
                                             float* __restrict__ out) {
    int lane = threadIdx.x & 63;
    int wid  = threadIdx.x >> 6;
    int n = blockIdx.x * 4 + wid;
    unsigned cnt = rowlen[n];
    const unsigned short* rp = rowidx + (size_t)n * RBCAP;
    int v0 = rp[lane];
    int v1 = rp[64  + lane];
    int v2 = rp[128 + lane];
    float a0 = 0.f, a1 = 0.f, a2 = 0.f, a3 = 0.f;
    float a4 = 0.f, a5 = 0.f, a6 = 0.f, a7 = 0.f;
    SEG_GATHER(v0,   0u, cnt, t, a0, a1, a2, a3, a4, a5, a6, a7)
    SEG_GATHER(v1,  64u, cnt, t, a0, a1, a2, a3, a4, a5, a6, a7)
    SEG_GATHER(v2, 128u, cnt, t, a0, a1, a2, a3, a4, a5, a6, a7)
    float acc = ((a0 + a1) + (a2 + a3)) + ((a4 + a5) + (a6 + a7));
    float dvis = rsqrtf(fmaxf(Dv_raw[n], 1e-6f));
    out[(size_t)n * OUT_F + lane] = dvis * acc;
}

// ---------------------------------------------------------------------------
extern "C" void kernel_launch(void* const* d_in, const int* in_sizes, int n_in,
                              void* d_out, int out_size, void* d_ws, size_t ws_size,
                              hipStream_t stream) {
    const float* x  = (const float*)d_in[0];
    const float* H  = (const float*)d_in[1];
    const float* w  = (const float*)d_in[2];
    const float* Wl = (const float*)d_in[3];
    const float* bl = (const float*)d_in[4];
    float* out = (float*)d_out;

    // workspace (~31.7 MB):
    // y2[N*64] | t[M*64] | Dv[N] | rowlen[N] | cscfill[M]
    // | rowidx[N*RBCAP] ushort | cscidx[M*COLCAP] ushort
    float*    y2      = (float*)d_ws;
    float*    t       = y2 + (size_t)N_NODES * OUT_F;
    float*    Dv_raw  = t + (size_t)M_EDGES * OUT_F;
    unsigned* rowlen  = (unsigned*)(Dv_raw + N_NODES);
    unsigned* cscfill = rowlen + N_NODES;
    unsigned short* rowidx = (unsigned short*)(cscfill + M_EDGES);
    unsigned short* cscidx = rowidx + (size_t)N_NODES * RBCAP;

    hipMemsetAsync(cscfill, 0, M_EDGES * sizeof(unsigned), stream);

    k_scan<<<dim3(NBLK),         dim3(256), 0, stream>>>(H, rowidx, rowlen);
    k_csc <<<dim3(N_NODES / 4),  dim3(256), 0, stream>>>(rowidx, rowlen, w, cscidx, cscfill, Dv_raw);
    k_lin <<<dim3(N_NODES / 16), dim3(256), 0, stream>>>(x, Wl, bl, Dv_raw, y2);
    k_edge<<<dim3(M_EDGES / 4),  dim3(256), 0, stream>>>(cscidx, cscfill, w, y2, t);
    k_out <<<dim3(N_NODES / 4),  dim3(256), 0, stream>>>(rowidx, rowlen, t, Dv_raw, out);
}

// Round 7
// 1587.194 us; speedup vs baseline: 4.0908x; 1.0124x over previous
//
#include <hip/hip_runtime.h>

#define N_NODES 32768
#define M_EDGES 8192
#define IN_DIM  256
#define OUT_F   64

#define SCAN_ROWS 16                  // rows per scan block
#define NBLK   (N_NODES / SCAN_ROWS)  // 2048 scan blocks
#define RBCAP  192                    // per-row nz cap (mean 82, +12 sigma)
#define COLCAP 512                    // per-edge node cap (mean 328, +10 sigma)

// ---------------------------------------------------------------------------
// Pass 1: the single full H read (1.07 GB). BRANCH-FREE bitmask scan:
// hot loop is loads + compare/pack into 4 per-lane 32-bit mask registers —
// no stores, no ballots, no branches, so the compiler can keep 8 float4
// loads in flight. Emission (prefix-scan + ~2 store insts) happens once per
// row. Index order within a row is NOT sorted (sums are order-invariant).
// ---------------------------------------------------------------------------
__global__ __launch_bounds__(256) void k_scan(const float* __restrict__ H,
                                              unsigned short* __restrict__ rowidx,
                                              unsigned* __restrict__ rowlen) {
    int tid  = threadIdx.x;
    int lane = tid & 63;
    int wid  = tid >> 6;
    int row0 = blockIdx.x * SCAN_ROWS;

    for (int rr = wid; rr < SCAN_ROWS; rr += 4) {
        int n = row0 + rr;
        const float4* Hrow = (const float4*)(H + (size_t)n * M_EDGES);
        unsigned short* out_r = rowidx + (size_t)n * RBCAP;

        unsigned mreg[4];
        #pragma unroll
        for (int ob = 0; ob < 4; ++ob) {       // 4 outer blocks of 512 float4s
            int jb = ob * 512;
            float4 h0 = Hrow[jb + lane];
            float4 h1 = Hrow[jb + 64  + lane];
            float4 h2 = Hrow[jb + 128 + lane];
            float4 h3 = Hrow[jb + 192 + lane];
            float4 h4 = Hrow[jb + 256 + lane];
            float4 h5 = Hrow[jb + 320 + lane];
            float4 h6 = Hrow[jb + 384 + lane];
            float4 h7 = Hrow[jb + 448 + lane];
            unsigned mk = 0;
            #define PK(hv, g)                                                  \
            {                                                                  \
                unsigned b = (unsigned)(hv.x != 0.f)                           \
                           | ((unsigned)(hv.y != 0.f) << 1)                    \
                           | ((unsigned)(hv.z != 0.f) << 2)                    \
                           | ((unsigned)(hv.w != 0.f) << 3);                   \
                mk |= b << (4 * (g));                                          \
            }
            PK(h0, 0) PK(h1, 1) PK(h2, 2) PK(h3, 3)
            PK(h4, 4) PK(h5, 5) PK(h6, 6) PK(h7, 7)
            #undef PK
            mreg[ob] = mk;
        }

        // per-lane count + wave exclusive prefix (6-step shfl scan)
        unsigned cnt = (unsigned)(__popc(mreg[0]) + __popc(mreg[1])
                                + __popc(mreg[2]) + __popc(mreg[3]));
        unsigned incl = cnt;
        #pragma unroll
        for (int off = 1; off < 64; off <<= 1) {
            unsigned v = (unsigned)__shfl_up((int)incl, off, 64);
            if (lane >= off) incl += v;
        }
        unsigned pos = incl - cnt;                       // exclusive prefix
        unsigned total = (unsigned)__shfl((int)incl, 63, 64);

        // emit: bit p of mreg[r] -> m = r*2048 + (p>>2)*256 + lane*4 + (p&3)
        #pragma unroll
        for (int r = 0; r < 4; ++r) {
            unsigned m = mreg[r];
            while (m) {
                int p = __ffs(m) - 1;
                int g = p >> 2;
                int c = p & 3;
                int m_idx = r * 2048 + g * 256 + (lane << 2) + c;
                if (pos < RBCAP) out_r[pos] = (unsigned short)m_idx;
                ++pos;
                m &= m - 1;
            }
        }
        if (lane == 63)
            rowlen[n] = (total < (unsigned)RBCAP) ? total : (unsigned)RBCAP;
    }
}

// ---------------------------------------------------------------------------
// Pass 2: CSR -> fixed-stride CSC + Dv. Lane-parallel independent returning
// atomics (64 in flight per wave, 8192 counters).
// ---------------------------------------------------------------------------
__global__ __launch_bounds__(256) void k_csc(const unsigned short* __restrict__ rowidx,
                                             const unsigned* __restrict__ rowlen,
                                             const float* __restrict__ w,
                                             unsigned short* __restrict__ cscidx,
                                             unsigned* __restrict__ cscfill,
                                             float* __restrict__ Dv_raw) {
    int lane = threadIdx.x & 63;
    int wid  = threadIdx.x >> 6;
    int n = blockIdx.x * 4 + wid;
    unsigned cnt = rowlen[n];
    float dv = 0.f;
    for (unsigned j = lane; j < cnt; j += 64) {
        int m = rowidx[(size_t)n * RBCAP + j];
        dv += w[m];
        unsigned p = atomicAdd(&cscfill[m], 1u);
        if (p < (unsigned)COLCAP)
            cscidx[(size_t)m * COLCAP + p] = (unsigned short)n;
    }
    for (int off = 32; off; off >>= 1) dv += __shfl_down(dv, off, 64);
    if (lane == 0) Dv_raw[n] = dv;
}

// ---------------------------------------------------------------------------
// Pass 3: y2[n,k] = rsqrt(max(Dv[n],1e-6)) * (x[n,:] @ W[:,k] + b[k])
// ---------------------------------------------------------------------------
__global__ __launch_bounds__(256) void k_lin(const float* __restrict__ x,
                                             const float* __restrict__ Wl,
                                             const float* __restrict__ b,
                                             const float* __restrict__ Dv_raw,
                                             float* __restrict__ y2) {
    __shared__ float x_s[16 * IN_DIM];   // 16 KB
    int tid = threadIdx.x;
    int n0 = blockIdx.x * 16;
    for (int i = tid; i < 16 * IN_DIM; i += 256)
        x_s[i] = x[(size_t)n0 * IN_DIM + i];
    __syncthreads();
    int k = tid & 63;
    int rbase = tid >> 6;
    for (int pass = 0; pass < 4; ++pass) {
        int r = pass * 4 + rbase;
        float acc = b[k];
        const float* xr = x_s + r * IN_DIM;
        #pragma unroll 8
        for (int i = 0; i < IN_DIM; ++i)
            acc = fmaf(xr[i], Wl[i * OUT_F + k], acc);
        float dvis = rsqrtf(fmaxf(Dv_raw[n0 + r], 1e-6f));
        y2[(size_t)(n0 + r) * OUT_F + k] = acc * dvis;
    }
}

// Gather macro: one 64-entry segment held lane-parallel in register `vi`;
// readlane broadcast (no memory dependency), 8 gathers in flight.
#define SEG_GATHER(vi, base, cnt, src, acc0, acc1, acc2, acc3, acc4, acc5, acc6, acc7) \
{                                                                              \
    unsigned end = ((cnt) > (base)) ? ((cnt) - (base)) : 0u;                   \
    if (end > 64u) end = 64u;                                                  \
    unsigned sj = 0;                                                           \
    for (; sj + 8 <= end; sj += 8) {                                           \
        int m0 = __builtin_amdgcn_readlane(vi, sj + 0);                        \
        int m1 = __builtin_amdgcn_readlane(vi, sj + 1);                        \
        int m2 = __builtin_amdgcn_readlane(vi, sj + 2);                        \
        int m3 = __builtin_amdgcn_readlane(vi, sj + 3);                        \
        int m4 = __builtin_amdgcn_readlane(vi, sj + 4);                        \
        int m5 = __builtin_amdgcn_readlane(vi, sj + 5);                        \
        int m6 = __builtin_amdgcn_readlane(vi, sj + 6);                        \
        int m7 = __builtin_amdgcn_readlane(vi, sj + 7);                        \
        acc0 += src[(size_t)m0 * OUT_F + lane];                                \
        acc1 += src[(size_t)m1 * OUT_F + lane];                                \
        acc2 += src[(size_t)m2 * OUT_F + lane];                                \
        acc3 += src[(size_t)m3 * OUT_F + lane];                                \
        acc4 += src[(size_t)m4 * OUT_F + lane];                                \
        acc5 += src[(size_t)m5 * OUT_F + lane];                                \
        acc6 += src[(size_t)m6 * OUT_F + lane];                                \
        acc7 += src[(size_t)m7 * OUT_F + lane];                                \
    }                                                                          \
    for (; sj < end; ++sj) {                                                   \
        int mm = __builtin_amdgcn_readlane(vi, sj);                            \
        acc0 += src[(size_t)mm * OUT_F + lane];                                \
    }                                                                          \
}

// ---------------------------------------------------------------------------
// Pass 4: t'[m,:] = (w[m]/max(De[m],1)) * sum_{n in edge m} y2[n,:]
// ---------------------------------------------------------------------------
__global__ __launch_bounds__(256) void k_edge(const unsigned short* __restrict__ cscidx,
                                              const unsigned* __restrict__ cscfill,
                                              const float* __restrict__ w,
                                              const float* __restrict__ y2,
                                              float* __restrict__ t) {
    int lane = threadIdx.x & 63;
    int wid  = threadIdx.x >> 6;
    int m = blockIdx.x * 4 + wid;
    unsigned de = cscfill[m];
    unsigned cnt = (de < (unsigned)COLCAP) ? de : (unsigned)COLCAP;
    const unsigned short* cp = cscidx + (size_t)m * COLCAP;
    int v0 = cp[lane];         int v1 = cp[64  + lane];
    int v2 = cp[128 + lane];   int v3 = cp[192 + lane];
    int v4 = cp[256 + lane];   int v5 = cp[320 + lane];
    int v6 = cp[384 + lane];   int v7 = cp[448 + lane];
    float a0 = 0.f, a1 = 0.f, a2 = 0.f, a3 = 0.f;
    float a4 = 0.f, a5 = 0.f, a6 = 0.f, a7 = 0.f;
    SEG_GATHER(v0,   0u, cnt, y2, a0, a1, a2, a3, a4, a5, a6, a7)
    SEG_GATHER(v1,  64u, cnt, y2, a0, a1, a2, a3, a4, a5, a6, a7)
    SEG_GATHER(v2, 128u, cnt, y2, a0, a1, a2, a3, a4, a5, a6, a7)
    SEG_GATHER(v3, 192u, cnt, y2, a0, a1, a2, a3, a4, a5, a6, a7)
    SEG_GATHER(v4, 256u, cnt, y2, a0, a1, a2, a3, a4, a5, a6, a7)
    SEG_GATHER(v5, 320u, cnt, y2, a0, a1, a2, a3, a4, a5, a6, a7)
    SEG_GATHER(v6, 384u, cnt, y2, a0, a1, a2, a3, a4, a5, a6, a7)
    SEG_GATHER(v7, 448u, cnt, y2, a0, a1, a2, a3, a4, a5, a6, a7)
    float acc = ((a0 + a1) + (a2 + a3)) + ((a4 + a5) + (a6 + a7));
    float sc = w[m] / fmaxf((float)de, 1.0f);
    t[(size_t)m * OUT_F + lane] = acc * sc;
}

// ---------------------------------------------------------------------------
// Pass 5: out[n,:] = dvis[n] * sum_{m in row n} t'[m,:]
// ---------------------------------------------------------------------------
__global__ __launch_bounds__(256) void k_out(const unsigned short* __restrict__ rowidx,
                                             const unsigned* __restrict__ rowlen,
                                             const float* __restrict__ t,
                                             const float* __restrict__ Dv_raw,
                                             float* __restrict__ out) {
    int lane = threadIdx.x & 63;
    int wid  = threadIdx.x >> 6;
    int n = blockIdx.x * 4 + wid;
    unsigned cnt = rowlen[n];
    const unsigned short* rp = rowidx + (size_t)n * RBCAP;
    int v0 = rp[lane];
    int v1 = rp[64  + lane];
    int v2 = rp[128 + lane];
    float a0 = 0.f, a1 = 0.f, a2 = 0.f, a3 = 0.f;
    float a4 = 0.f, a5 = 0.f, a6 = 0.f, a7 = 0.f;
    SEG_GATHER(v0,   0u, cnt, t, a0, a1, a2, a3, a4, a5, a6, a7)
    SEG_GATHER(v1,  64u, cnt, t, a0, a1, a2, a3, a4, a5, a6, a7)
    SEG_GATHER(v2, 128u, cnt, t, a0, a1, a2, a3, a4, a5, a6, a7)
    float acc = ((a0 + a1) + (a2 + a3)) + ((a4 + a5) + (a6 + a7));
    float dvis = rsqrtf(fmaxf(Dv_raw[n], 1e-6f));
    out[(size_t)n * OUT_F + lane] = dvis * acc;
}

// ---------------------------------------------------------------------------
extern "C" void kernel_launch(void* const* d_in, const int* in_sizes, int n_in,
                              void* d_out, int out_size, void* d_ws, size_t ws_size,
                              hipStream_t stream) {
    const float* x  = (const float*)d_in[0];
    const float* H  = (const float*)d_in[1];
    const float* w  = (const float*)d_in[2];
    const float* Wl = (const float*)d_in[3];
    const float* bl = (const float*)d_in[4];
    float* out = (float*)d_out;

    // workspace (~31.7 MB):
    // y2[N*64] | t[M*64] | Dv[N] | rowlen[N] | cscfill[M]
    // | rowidx[N*RBCAP] ushort | cscidx[M*COLCAP] ushort
    float*    y2      = (float*)d_ws;
    float*    t       = y2 + (size_t)N_NODES * OUT_F;
    float*    Dv_raw  = t + (size_t)M_EDGES * OUT_F;
    unsigned* rowlen  = (unsigned*)(Dv_raw + N_NODES);
    unsigned* cscfill = rowlen + N_NODES;
    unsigned short* rowidx = (unsigned short*)(cscfill + M_EDGES);
    unsigned short* cscidx = rowidx + (size_t)N_NODES * RBCAP;

    hipMemsetAsync(cscfill, 0, M_EDGES * sizeof(unsigned), stream);

    k_scan<<<dim3(NBLK),         dim3(256), 0, stream>>>(H, rowidx, rowlen);
    k_csc <<<dim3(N_NODES / 4),  dim3(256), 0, stream>>>(rowidx, rowlen, w, cscidx, cscfill, Dv_raw);
    k_lin <<<dim3(N_NODES / 16), dim3(256), 0, stream>>>(x, Wl, bl, Dv_raw, y2);
    k_edge<<<dim3(M_EDGES / 4),  dim3(256), 0, stream>>>(cscidx, cscfill, w, y2, t);
    k_out <<<dim3(N_NODES / 4),  dim3(256), 0, stream>>>(rowidx, rowlen, t, Dv_raw, out);
}

// Round 8
// 1540.649 us; speedup vs baseline: 4.2144x; 1.0302x over previous
//
#include <hip/hip_runtime.h>

#define N_NODES 32768
#define M_EDGES 8192
#define IN_DIM  256
#define OUT_F   64

#define SCAN_ROWS 16                  // rows per scan block
#define NBLK   (N_NODES / SCAN_ROWS)  // 2048 scan blocks
#define RBCAP  192                    // per-row nz cap (mean 82, +12 sigma)
#define COLCAP 512                    // per-edge node cap (mean 328, +10 sigma)

// ---------------------------------------------------------------------------
// Pass 1 (fused): the single full H read (1.07 GB), branch-free bitmask scan.
// Per-row epilogue emits: CSR indices, CSC scatter (returning atomic + 2B
// store, lane-parallel, hidden under next row's loads), Dv (w-gather), rowlen.
// ---------------------------------------------------------------------------
__global__ __launch_bounds__(256) void k_scan(const float* __restrict__ H,
                                              const float* __restrict__ w,
                                              unsigned short* __restrict__ rowidx,
                                              unsigned* __restrict__ rowlen,
                                              unsigned short* __restrict__ cscidx,
                                              unsigned* __restrict__ cscfill,
                                              float* __restrict__ Dv_raw) {
    int tid  = threadIdx.x;
    int lane = tid & 63;
    int wid  = tid >> 6;
    int row0 = blockIdx.x * SCAN_ROWS;

    for (int rr = wid; rr < SCAN_ROWS; rr += 4) {
        int n = row0 + rr;
        const float4* Hrow = (const float4*)(H + (size_t)n * M_EDGES);
        unsigned short* out_r = rowidx + (size_t)n * RBCAP;

        unsigned mreg[4];
        #pragma unroll
        for (int ob = 0; ob < 4; ++ob) {       // 4 outer blocks of 512 float4s
            int jb = ob * 512;
            float4 h0 = Hrow[jb + lane];
            float4 h1 = Hrow[jb + 64  + lane];
            float4 h2 = Hrow[jb + 128 + lane];
            float4 h3 = Hrow[jb + 192 + lane];
            float4 h4 = Hrow[jb + 256 + lane];
            float4 h5 = Hrow[jb + 320 + lane];
            float4 h6 = Hrow[jb + 384 + lane];
            float4 h7 = Hrow[jb + 448 + lane];
            unsigned mk = 0;
            #define PK(hv, g)                                                  \
            {                                                                  \
                unsigned b = (unsigned)(hv.x != 0.f)                           \
                           | ((unsigned)(hv.y != 0.f) << 1)                    \
                           | ((unsigned)(hv.z != 0.f) << 2)                    \
                           | ((unsigned)(hv.w != 0.f) << 3);                   \
                mk |= b << (4 * (g));                                          \
            }
            PK(h0, 0) PK(h1, 1) PK(h2, 2) PK(h3, 3)
            PK(h4, 4) PK(h5, 5) PK(h6, 6) PK(h7, 7)
            #undef PK
            mreg[ob] = mk;
        }

        // per-lane count + wave exclusive prefix (6-step shfl scan)
        unsigned cnt = (unsigned)(__popc(mreg[0]) + __popc(mreg[1])
                                + __popc(mreg[2]) + __popc(mreg[3]));
        unsigned incl = cnt;
        #pragma unroll
        for (int off = 1; off < 64; off <<= 1) {
            unsigned v = (unsigned)__shfl_up((int)incl, off, 64);
            if (lane >= off) incl += v;
        }
        unsigned pos = incl - cnt;                       // exclusive prefix
        unsigned total = (unsigned)__shfl((int)incl, 63, 64);

        // emit: bit p of mreg[r] -> m = r*2048 + (p>>2)*256 + lane*4 + (p&3)
        float dv = 0.f;
        #pragma unroll
        for (int r = 0; r < 4; ++r) {
            unsigned mm = mreg[r];
            while (mm) {
                int p = __ffs(mm) - 1;
                int g = p >> 2;
                int c4 = p & 3;
                int m_idx = r * 2048 + g * 256 + (lane << 2) + c4;
                if (pos < RBCAP) out_r[pos] = (unsigned short)m_idx;
                ++pos;
                dv += w[m_idx];
                unsigned fp = atomicAdd(&cscfill[m_idx], 1u);
                if (fp < (unsigned)COLCAP)
                    cscidx[(size_t)m_idx * COLCAP + fp] = (unsigned short)n;
                mm &= mm - 1;
            }
        }
        for (int off = 32; off; off >>= 1) dv += __shfl_down(dv, off, 64);
        if (lane == 0) Dv_raw[n] = dv;
        if (lane == 63)
            rowlen[n] = (total < (unsigned)RBCAP) ? total : (unsigned)RBCAP;
    }
}

// ---------------------------------------------------------------------------
// Pass 2: y2[n,k] = rsqrt(max(Dv[n],1e-6)) * (x[n,:] @ W[:,k] + b[k])
// ---------------------------------------------------------------------------
__global__ __launch_bounds__(256) void k_lin(const float* __restrict__ x,
                                             const float* __restrict__ Wl,
                                             const float* __restrict__ b,
                                             const float* __restrict__ Dv_raw,
                                             float* __restrict__ y2) {
    __shared__ float x_s[16 * IN_DIM];   // 16 KB
    int tid = threadIdx.x;
    int n0 = blockIdx.x * 16;
    for (int i = tid; i < 16 * IN_DIM; i += 256)
        x_s[i] = x[(size_t)n0 * IN_DIM + i];
    __syncthreads();
    int k = tid & 63;
    int rbase = tid >> 6;
    for (int pass = 0; pass < 4; ++pass) {
        int r = pass * 4 + rbase;
        float acc = b[k];
        const float* xr = x_s + r * IN_DIM;
        #pragma unroll 8
        for (int i = 0; i < IN_DIM; ++i)
            acc = fmaf(xr[i], Wl[i * OUT_F + k], acc);
        float dvis = rsqrtf(fmaxf(Dv_raw[n0 + r], 1e-6f));
        y2[(size_t)(n0 + r) * OUT_F + k] = acc * dvis;
    }
}

// Quad-row gather segment: lane L (g=L/16, c=L%16) loads float4 of row
// idx[4q+g] -> 4 rows per 1 KB load instruction; per-entry validity masked.
#define SEGQ(vi, base, cnt, src, ax, ay, az, aw, g, c, lane)                   \
if ((base) < (cnt)) {                                                          \
    unsigned rem = (cnt) - (base); if (rem > 64u) rem = 64u;                   \
    unsigned nq = (rem + 3u) >> 2;                                             \
    _Pragma("unroll 4")                                                        \
    for (unsigned qq = 0; qq < nq; ++qq) {                                     \
        int nidx = __shfl(vi, (int)(4u * qq) + (g), 64);                       \
        const float4* srcp = (const float4*)((src) + (size_t)nidx * OUT_F);    \
        float4 v = srcp[c];                                                    \
        bool ok = (4u * qq + (unsigned)(g)) < rem;                             \
        ax += ok ? v.x : 0.f;                                                  \
        ay += ok ? v.y : 0.f;                                                  \
        az += ok ? v.z : 0.f;                                                  \
        aw += ok ? v.w : 0.f;                                                  \
    }                                                                          \
}

// ---------------------------------------------------------------------------
// Pass 3: t'[m,:] = (w[m]/max(De[m],1)) * sum_{n in edge m} y2[n,:]
// One wave per edge; quad-row float4 gathers; 2-shfl cross-group reduce;
// 16-lane dwordx4 store. No atomics.
// ---------------------------------------------------------------------------
__global__ __launch_bounds__(256) void k_edge(const unsigned short* __restrict__ cscidx,
                                              const unsigned* __restrict__ cscfill,
                                              const float* __restrict__ w,
                                              const float* __restrict__ y2,
                                              float* __restrict__ t) {
    int lane = threadIdx.x & 63;
    int wid  = threadIdx.x >> 6;
    int m = blockIdx.x * 4 + wid;
    unsigned de = cscfill[m];
    unsigned cnt = (de < (unsigned)COLCAP) ? de : (unsigned)COLCAP;
    const unsigned short* cp = cscidx + (size_t)m * COLCAP;
    int g = lane >> 4;
    int c = lane & 15;
    int v0 = cp[lane];         int v1 = cp[64  + lane];
    int v2 = cp[128 + lane];   int v3 = cp[192 + lane];
    int v4 = cp[256 + lane];   int v5 = cp[320 + lane];
    int v6 = cp[384 + lane];   int v7 = cp[448 + lane];
    float ax = 0.f, ay = 0.f, az = 0.f, aw = 0.f;
    SEGQ(v0,   0u, cnt, y2, ax, ay, az, aw, g, c, lane)
    SEGQ(v1,  64u, cnt, y2, ax, ay, az, aw, g, c, lane)
    SEGQ(v2, 128u, cnt, y2, ax, ay, az, aw, g, c, lane)
    SEGQ(v3, 192u, cnt, y2, ax, ay, az, aw, g, c, lane)
    SEGQ(v4, 256u, cnt, y2, ax, ay, az, aw, g, c, lane)
    SEGQ(v5, 320u, cnt, y2, ax, ay, az, aw, g, c, lane)
    SEGQ(v6, 384u, cnt, y2, ax, ay, az, aw, g, c, lane)
    SEGQ(v7, 448u, cnt, y2, ax, ay, az, aw, g, c, lane)
    ax += __shfl_xor(ax, 16, 64); ax += __shfl_xor(ax, 32, 64);
    ay += __shfl_xor(ay, 16, 64); ay += __shfl_xor(ay, 32, 64);
    az += __shfl_xor(az, 16, 64); az += __shfl_xor(az, 32, 64);
    aw += __shfl_xor(aw, 16, 64); aw += __shfl_xor(aw, 32, 64);
    if (g == 0) {
        float sc = w[m] / fmaxf((float)de, 1.0f);
        float4 r4 = { ax * sc, ay * sc, az * sc, aw * sc };
        ((float4*)(t + (size_t)m * OUT_F))[c] = r4;
    }
}

// ---------------------------------------------------------------------------
// Pass 4: out[n,:] = dvis[n] * sum_{m in row n} t'[m,:].  Same quad-gather.
// ---------------------------------------------------------------------------
__global__ __launch_bounds__(256) void k_out(const unsigned short* __restrict__ rowidx,
                                             const unsigned* __restrict__ rowlen,
                                             const float* __restrict__ t,
                                             const float* __restrict__ Dv_raw,
                                             float* __restrict__ out) {
    int lane = threadIdx.x & 63;
    int wid  = threadIdx.x >> 6;
    int n = blockIdx.x * 4 + wid;
    unsigned cnt = rowlen[n];
    const unsigned short* rp = rowidx + (size_t)n * RBCAP;
    int g = lane >> 4;
    int c = lane & 15;
    int v0 = rp[lane];
    int v1 = rp[64  + lane];
    int v2 = rp[128 + lane];
    float ax = 0.f, ay = 0.f, az = 0.f, aw = 0.f;
    SEGQ(v0,   0u, cnt, t, ax, ay, az, aw, g, c, lane)
    SEGQ(v1,  64u, cnt, t, ax, ay, az, aw, g, c, lane)
    SEGQ(v2, 128u, cnt, t, ax, ay, az, aw, g, c, lane)
    ax += __shfl_xor(ax, 16, 64); ax += __shfl_xor(ax, 32, 64);
    ay += __shfl_xor(ay, 16, 64); ay += __shfl_xor(ay, 32, 64);
    az += __shfl_xor(az, 16, 64); az += __shfl_xor(az, 32, 64);
    aw += __shfl_xor(aw, 16, 64); aw += __shfl_xor(aw, 32, 64);
    if (g == 0) {
        float dvis = rsqrtf(fmaxf(Dv_raw[n], 1e-6f));
        float4 r4 = { ax * dvis, ay * dvis, az * dvis, aw * dvis };
        ((float4*)(out + (size_t)n * OUT_F))[c] = r4;
    }
}

// ---------------------------------------------------------------------------
extern "C" void kernel_launch(void* const* d_in, const int* in_sizes, int n_in,
                              void* d_out, int out_size, void* d_ws, size_t ws_size,
                              hipStream_t stream) {
    const float* x  = (const float*)d_in[0];
    const float* H  = (const float*)d_in[1];
    const float* w  = (const float*)d_in[2];
    const float* Wl = (const float*)d_in[3];
    const float* bl = (const float*)d_in[4];
    float* out = (float*)d_out;

    // workspace (~31.7 MB):
    // y2[N*64] | t[M*64] | Dv[N] | rowlen[N] | cscfill[M]
    // | rowidx[N*RBCAP] ushort | cscidx[M*COLCAP] ushort
    float*    y2      = (float*)d_ws;
    float*    t       = y2 + (size_t)N_NODES * OUT_F;
    float*    Dv_raw  = t + (size_t)M_EDGES * OUT_F;
    unsigned* rowlen  = (unsigned*)(Dv_raw + N_NODES);
    unsigned* cscfill = rowlen + N_NODES;
    unsigned short* rowidx = (unsigned short*)(cscfill + M_EDGES);
    unsigned short* cscidx = rowidx + (size_t)N_NODES * RBCAP;

    hipMemsetAsync(cscfill, 0, M_EDGES * sizeof(unsigned), stream);

    k_scan<<<dim3(NBLK),         dim3(256), 0, stream>>>(H, w, rowidx, rowlen, cscidx, cscfill, Dv_raw);
    k_lin <<<dim3(N_NODES / 16), dim3(256), 0, stream>>>(x, Wl, bl, Dv_raw, y2);
    k_edge<<<dim3(M_EDGES / 4),  dim3(256), 0, stream>>>(cscidx, cscfill, w, y2, t);
    k_out <<<dim3(N_NODES / 4),  dim3(256), 0, stream>>>(rowidx, rowlen, t, Dv_raw, out);
}